// Round 12
// baseline (60.757 us; speedup 1.0000x reference)
//
#include <hip/hip_runtime.h>
#include <math.h>

typedef __bf16 bf16_t;
typedef __bf16 bf16x8 __attribute__((ext_vector_type(8)));
typedef float f32x4 __attribute__((ext_vector_type(4)));
typedef unsigned int u32;

// Problem constants
#define M_ROWS 7680      // bs(4) * seq(32) * 60 patches
#define N1 512
#define K1 1024
#define NPX 160
#define NPY 96
#define BDIM 128         // bs*seq
#define NPATCH 60
#define NPIX (BDIM*NPX*NPY)

// ws float offsets
#define OFF_WGEFF   0                        // 512*3
#define OFF_BIASEFF 1536                     // 3 (pad to 2048)
#define OFF_CF      2048                     // 15360*3 = 46080
#define OFF_HWPART  71168                    // 8*7680*3 = 184320
#define OFF_W1T     255488                   // bf16[512*1024] = 262144 float slots

// GEMM tiling
#define BM 64
#define BN 64
#define BK 64

static __device__ __forceinline__ void gll16(const void* g, void* l) {
    __builtin_amdgcn_global_load_lds(
        (const __attribute__((address_space(1))) u32*)g,
        (__attribute__((address_space(3))) u32*)l, 16, 0, 0);
}

static __device__ inline bf16x8 cvt8(float4 a, float4 b) {
    bf16x8 v;
    v[0] = (bf16_t)a.x; v[1] = (bf16_t)a.y; v[2] = (bf16_t)a.z; v[3] = (bf16_t)a.w;
    v[4] = (bf16_t)b.x; v[5] = (bf16_t)b.y; v[6] = (bf16_t)b.z; v[7] = (bf16_t)b.w;
    return v;
}

// ---------------------------------------------------------------------------
// Prep (A-convert REMOVED): blocks 0..127 transpose W1 -> W1T bf16;
// block 128 Wg_eff + bias_eff; blocks 129..308 coordinate field cf.
__global__ __launch_bounds__(256) void prep_kernel(
    const float* __restrict__ W1, const float* __restrict__ W2,
    const float* __restrict__ b2, const float* __restrict__ Wg,
    const float* __restrict__ bg, float* __restrict__ ws)
{
    const int t = threadIdx.x;
    if (blockIdx.x < 128) {
        __shared__ bf16_t tile[64][72];
        const int k0 = (blockIdx.x & 15) * 64;
        const int n0 = (blockIdx.x >> 4) * 64;
        bf16_t* W1T = (bf16_t*)(ws + OFF_W1T);
#pragma unroll
        for (int i = 0; i < 4; ++i) {
            int idx = t + i * 256;
            int r = idx >> 4, ch = idx & 15;
            float4 v = *(const float4*)(W1 + (size_t)(k0 + r) * N1 + n0 + ch * 4);
            bf16_t* dst = &tile[r][ch * 4];
            dst[0] = (bf16_t)v.x; dst[1] = (bf16_t)v.y;
            dst[2] = (bf16_t)v.z; dst[3] = (bf16_t)v.w;
        }
        __syncthreads();
#pragma unroll
        for (int i = 0; i < 2; ++i) {
            int idx = t + i * 256;
            int nr = idx >> 3, kc = idx & 7;
            bf16x8 o;
#pragma unroll
            for (int j = 0; j < 8; ++j) o[j] = tile[kc * 8 + j][nr];
            *(bf16x8*)(W1T + (size_t)(n0 + nr) * K1 + k0 + kc * 8) = o;
        }
    } else if (blockIdx.x == 128) {
#pragma unroll
        for (int rep = 0; rep < 2; ++rep) {
            int j = t + rep * 256;
            float a0 = 0.f, a1 = 0.f, a2 = 0.f;
            for (int k = 0; k < 128; ++k) {
                float w = W2[j * 128 + k];
                a0 = fmaf(w, Wg[k * 3 + 0], a0);
                a1 = fmaf(w, Wg[k * 3 + 1], a1);
                a2 = fmaf(w, Wg[k * 3 + 2], a2);
            }
            ws[OFF_WGEFF + j * 3 + 0] = a0;
            ws[OFF_WGEFF + j * 3 + 1] = a1;
            ws[OFF_WGEFF + j * 3 + 2] = a2;
        }
        if (t < 3) {
            float s = 0.f;
            for (int k = 0; k < 128; ++k) s = fmaf(b2[k], Wg[k * 3 + t], s);
            ws[OFF_BIASEFF + t] = s;
        }
    } else {
        int e = (blockIdx.x - 129) * 256 + t;    // < 46080 exactly
        int c = e % 3;
        int p = e / 3;
        int x = p / NPY, y = p % NPY;
        float wpx = Wg[128 * 3 + c], wpy = Wg[129 * 3 + c];
        float wqx = Wg[130 * 3 + c], wqy = Wg[131 * 3 + c];
        auto aff = [&](int xx, int yy) -> float {
            return (float)(xx >> 4) * wpx + (float)(yy >> 4) * wpy
                 + (float)(xx & 15) * (1.f / 15.f) * wqx
                 + (float)(yy & 15) * (1.f / 15.f) * wqy;
        };
        auto deg = [&](int xx, int yy) -> float {
            return 1.f + (xx > 0) + (xx < NPX - 1) + (yy > 0) + (yy < NPY - 1);
        };
        float degc = deg(x, y);
        float s = 0.f;
        if (x > 0)       s += rsqrtf(deg(x - 1, y)) * aff(x - 1, y);
        if (x < NPX - 1) s += rsqrtf(deg(x + 1, y)) * aff(x + 1, y);
        if (y > 0)       s += rsqrtf(deg(x, y - 1)) * aff(x, y - 1);
        if (y < NPY - 1) s += rsqrtf(deg(x, y + 1)) * aff(x, y + 1);
        ws[OFF_CF + e] = rsqrtf(degc) * s + aff(x, y) / degc + bg[c];
    }
}

// ---------------------------------------------------------------------------
// GEMM: A staged as F32 via global_load_lds (no prep convert, no ds_write);
// f32->bf16 cast happens in registers after ds_read_b128. B bf16 via gll
// (r11-verbatim). Both use the rule-#21 involution: source chunk ^ (row&7),
// same XOR on the read address. 960 blocks x 256 thr, 4 waves of 32x32,
// bijective XCD chunk swizzle. LDS 48 KB: A f32 [2][64][64] + B bf16 [2][64][64].
__global__ __launch_bounds__(256) void gemm_gll_kernel(
    const float* __restrict__ A,      // [7680,1024] f32
    const float* __restrict__ b1,     // [512]
    const float* __restrict__ ws,     // Wg_eff + W1T
    float* __restrict__ hw_part)      // [8][7680][3]
{
    __shared__ __align__(16) char smem[49152];
    float*  sAf = (float*)smem;                  // [2][64][64] f32 = 32 KB
    bf16_t* sB  = (bf16_t*)(smem + 32768);       // [2][64][64] bf16 = 16 KB
    float*  red = (float*)smem;                  // [64][32][3] (epilogue reuse)
    const bf16_t* W1T = (const bf16_t*)(ws + OFF_W1T);

    // XCD chunk swizzle (bijective: 960 = 8 * 120)
    const int bid = blockIdx.x;
    const int xcd = bid & 7;
    const int local = bid >> 3;                 // 0..119
    const int nblk = local & 7;                 // 0..7
    const int mblk = xcd * 15 + (local >> 3);   // 0..119
    const int m0 = mblk * BM;
    const int n0 = nblk * BN;

    const int t = threadIdx.x;
    const int lane = t & 63;
    const int wv = t >> 6;            // 0..3
    const int wr = wv >> 1, wc = wv & 1;
    const int l15 = lane & 15, hi = lane >> 4;
    const int x7 = l15 & 7;

    // ---- A staging: 4 gll/wave-instr per step, each covers 4 rows x 256 B.
    // instr i: row r = 4*(4*wv+i) + (lane>>4); lane chunk pos (lane&15);
    // source chunk = pos ^ (r&7)  [inverse swizzle at the source].
    const float* aSrc[4];
    int ldsA[4];
#pragma unroll
    for (int i = 0; i < 4; ++i) {
        int r = 4 * (4 * wv + i) + (lane >> 4);
        int csrc = (lane & 15) ^ (r & 7);
        aSrc[i] = A + (size_t)(m0 + r) * K1 + csrc * 4;
        ldsA[i] = (4 * wv + i) * 256;           // floats (wave-uniform base)
    }
    // ---- B staging (r11-verbatim): 2 gll/wave-instr per step, 8 rows x 128 B.
    const int rB0 = 8 * (2 * wv) + (lane >> 3);
    const int cB = (lane & 7) ^ (lane >> 3);
    const bf16_t* bSrc0 = W1T + (size_t)(n0 + rB0) * K1 + cB * 8;
    const bf16_t* bSrc1 = bSrc0 + (size_t)8 * K1;
    const int ldsB0 = (2 * wv + 0) * 512;       // bf16 elems
    const int ldsB1 = (2 * wv + 1) * 512;

    // fragment read offsets (swizzled)
    int aoff[2][2][2];   // [mi][kk][s] floats: row*64 + (kk*8 + ((hi*2+s)^(row&7)))*4
    int boff[2][2];      // [ni][kk]  bf16:    row*64 + ((kk*4+hi)^x7)*8
#pragma unroll
    for (int mi = 0; mi < 2; ++mi) {
        int r2 = wr * 32 + mi * 16 + l15;
#pragma unroll
        for (int kk = 0; kk < 2; ++kk)
#pragma unroll
            for (int s = 0; s < 2; ++s)
                aoff[mi][kk][s] = r2 * 64 + (kk * 8 + ((hi * 2 + s) ^ (r2 & 7))) * 4;
    }
#pragma unroll
    for (int ni = 0; ni < 2; ++ni)
#pragma unroll
        for (int kk = 0; kk < 2; ++kk)
            boff[ni][kk] = (wc * 32 + ni * 16 + l15) * 64 + ((kk * 4 + hi) ^ x7) * 8;

    f32x4 acc[2][2];
#pragma unroll
    for (int i = 0; i < 2; ++i)
#pragma unroll
        for (int j = 0; j < 2; ++j) acc[i][j] = (f32x4)0.f;

    // prologue: stage ks=0 into buffer 0
#pragma unroll
    for (int i = 0; i < 4; ++i) gll16(aSrc[i], sAf + ldsA[i]);
    gll16(bSrc0, sB + ldsB0);
    gll16(bSrc1, sB + ldsB1);
    __syncthreads();

    int cur = 0;
    for (int ks = 0; ks < K1 / BK; ++ks) {
        if (ks < K1 / BK - 1) {
            const int ka = (ks + 1) * BK;
            const int nbA = (cur ^ 1) * 4096;
#pragma unroll
            for (int i = 0; i < 4; ++i) gll16(aSrc[i] + ka, sAf + nbA + ldsA[i]);
            gll16(bSrc0 + ka, sB + nbA + ldsB0);
            gll16(bSrc1 + ka, sB + nbA + ldsB1);
        }
        const float*  cA = sAf + cur * 4096;
        const bf16_t* cB = sB + cur * 4096;
        bf16x8 af[2][2], bfr[2][2];
#pragma unroll
        for (int mi = 0; mi < 2; ++mi)
#pragma unroll
            for (int kk = 0; kk < 2; ++kk) {
                float4 v0 = *(const float4*)(cA + aoff[mi][kk][0]);
                float4 v1 = *(const float4*)(cA + aoff[mi][kk][1]);
                af[mi][kk] = cvt8(v0, v1);
            }
#pragma unroll
        for (int ni = 0; ni < 2; ++ni)
#pragma unroll
            for (int kk = 0; kk < 2; ++kk)
                bfr[ni][kk] = *(const bf16x8*)(cB + boff[ni][kk]);
#pragma unroll
        for (int kk = 0; kk < 2; ++kk)
#pragma unroll
            for (int mi = 0; mi < 2; ++mi)
#pragma unroll
                for (int ni = 0; ni < 2; ++ni)
                    acc[mi][ni] = __builtin_amdgcn_mfma_f32_16x16x32_bf16(
                        af[mi][kk], bfr[ni][kk], acc[mi][ni], 0, 0, 0);
        __syncthreads();
        cur ^= 1;
    }

    // epilogue: softplus + Wg_eff fold; per-lane partials -> LDS -> hw_part
    float b1v[2], wgv[2][3];
#pragma unroll
    for (int ni = 0; ni < 2; ++ni) {
        int n = n0 + wc * 32 + ni * 16 + l15;
        b1v[ni]    = b1[n];
        wgv[ni][0] = ws[OFF_WGEFF + n * 3 + 0];
        wgv[ni][1] = ws[OFF_WGEFF + n * 3 + 1];
        wgv[ni][2] = ws[OFF_WGEFF + n * 3 + 2];
    }
#pragma unroll
    for (int mi = 0; mi < 2; ++mi)
#pragma unroll
        for (int r = 0; r < 4; ++r) {
            float p0 = 0.f, p1 = 0.f, p2 = 0.f;
#pragma unroll
            for (int ni = 0; ni < 2; ++ni) {
                float z = acc[mi][ni][r] + b1v[ni];
                float sp = fmaxf(z, 0.f) + __logf(1.f + __expf(-fabsf(z)));
                p0 = fmaf(sp, wgv[ni][0], p0);
                p1 = fmaf(sp, wgv[ni][1], p1);
                p2 = fmaf(sp, wgv[ni][2], p2);
            }
            int ml = wr * 32 + mi * 16 + hi * 4 + r;   // 0..63 (bijective)
            int j  = wc * 16 + l15;                    // 0..31
            float* dst = red + (ml * 32 + j) * 3;
            dst[0] = p0; dst[1] = p1; dst[2] = p2;
        }
    __syncthreads();
    if (t < 192) {
        int m = t / 3, c = t - m * 3;
        float s = 0.f;
#pragma unroll
        for (int j = 0; j < 32; ++j) s += red[(m * 32 + j) * 3 + c];
        hw_part[((size_t)nblk * M_ROWS + m0 + m) * 3 + c] = s;
    }
}

// ---------------------------------------------------------------------------
// Fused hw-reduce + GCN stencil (r8/r10/r11-validated).
__global__ __launch_bounds__(384) void stencil_kernel(
    const float* __restrict__ ws, float* __restrict__ out)
{
    __shared__ float hwl[3][6][3];
    const int blk = blockIdx.x;
    const int b = blk / 10;
    const int px0 = blk % 10;
    const int x0 = px0 * 16;
    const int t = threadIdx.x;

    if (t < 54) {
        int j = t / 3, c = t - (t / 3) * 3;
        int dxi = j / 6, py = j % 6;
        int px = px0 - 1 + dxi;
        float v = 0.f;
        if (px >= 0 && px < 10) {
            int m = b * NPATCH + px * 6 + py;
            v = ws[OFF_BIASEFF + c];
#pragma unroll
            for (int s = 0; s < 8; ++s)
                v += ws[OFF_HWPART + ((size_t)s * M_ROWS + m) * 3 + c];
        }
        hwl[dxi][py][c] = v;
    }
    __syncthreads();

    const int xr = t / 24;
    const int y0 = (t - xr * 24) * 4;
    const int x = x0 + xr;
    const float* cf = ws + OFF_CF;

    auto deg = [&](int xx, int yy) -> float {
        return 1.f + (xx > 0) + (xx < NPX - 1) + (yy > 0) + (yy < NPY - 1);
    };
    auto hwp = [&](int xx, int yy) -> const float* {
        return &hwl[(xx >> 4) - (px0 - 1)][yy >> 4][0];
    };

    float res[4][3];
#pragma unroll
    for (int i = 0; i < 4; ++i) {
        int y = y0 + i;
        float degc = deg(x, y);
        float dinvc = rsqrtf(degc);
        float s0 = 0.f, s1 = 0.f, s2 = 0.f;
        auto tap = [&](int xx, int yy) {
            float dn = rsqrtf(deg(xx, yy));
            const float* h = hwp(xx, yy);
            s0 = fmaf(dn, h[0], s0);
            s1 = fmaf(dn, h[1], s1);
            s2 = fmaf(dn, h[2], s2);
        };
        if (x > 0)       tap(x - 1, y);
        if (x < NPX - 1) tap(x + 1, y);
        if (y > 0)       tap(x, y - 1);
        if (y < NPY - 1) tap(x, y + 1);
        const float* hs = hwp(x, y);
        const float* c = cf + (x * NPY + y) * 3;
        float inv_deg = 1.f / degc;
        res[i][0] = c[0] + fmaf(dinvc, s0, hs[0] * inv_deg);
        res[i][1] = c[1] + fmaf(dinvc, s1, hs[1] * inv_deg);
        res[i][2] = c[2] + fmaf(dinvc, s2, hs[2] * inv_deg);
    }
    float4 v0 = {res[0][0], res[0][1], res[0][2], res[1][0]};
    float4 v1 = {res[1][1], res[1][2], res[2][0], res[2][1]};
    float4 v2 = {res[2][2], res[3][0], res[3][1], res[3][2]};
    size_t p0 = ((size_t)b * NPX + x) * NPY + y0;
    float* o = out + p0 * 3;
    *(float4*)(o + 0) = v0;
    *(float4*)(o + 4) = v1;
    *(float4*)(o + 8) = v2;
}

// ---------------------------------------------------------------------------
extern "C" void kernel_launch(void* const* d_in, const int* in_sizes, int n_in,
                              void* d_out, int out_size, void* d_ws, size_t ws_size,
                              hipStream_t stream) {
    const float* pv = (const float*)d_in[0];
    const float* W1 = (const float*)d_in[1];
    const float* b1 = (const float*)d_in[2];
    const float* W2 = (const float*)d_in[3];
    const float* b2 = (const float*)d_in[4];
    const float* Wg = (const float*)d_in[5];
    const float* bg = (const float*)d_in[6];
    // d_in[7] = edge_index: fixed 4-neighbor grid, derived analytically

    float* ws = (float*)d_ws;
    float* out = (float*)d_out;

    hipLaunchKernelGGL(prep_kernel, dim3(309), dim3(256), 0, stream,
                       W1, W2, b2, Wg, bg, ws);
    hipLaunchKernelGGL(gemm_gll_kernel, dim3(960), dim3(256), 0, stream,
                       pv, b1, ws, ws + OFF_HWPART);
    hipLaunchKernelGGL(stencil_kernel, dim3(1280), dim3(384), 0, stream,
                       ws, out);
}

// Round 13
// 59.250 us; speedup vs baseline: 1.0254x; 1.0254x over previous
//
#include <hip/hip_runtime.h>
#include <math.h>

typedef __bf16 bf16_t;
typedef __bf16 bf16x8 __attribute__((ext_vector_type(8)));
typedef float f32x4 __attribute__((ext_vector_type(4)));
typedef unsigned int u32;

// Problem constants
#define M_ROWS 7680      // bs(4) * seq(32) * 60 patches
#define N1 512
#define K1 1024
#define NPX 160
#define NPY 96
#define BDIM 128         // bs*seq
#define NPATCH 60
#define NPIX (BDIM*NPX*NPY)

// ws float offsets
#define OFF_WGEFF   0                        // 512*3
#define OFF_BIASEFF 1536                     // 3 (pad to 2048)
#define OFF_CF      2048                     // 15360*3 = 46080
#define OFF_HWPART  71168                    // 8*7680*3 = 184320
#define OFF_W1T     255488                   // bf16[512*1024] = 262144 float slots

// GEMM tiling
#define BM 64
#define BN 64
#define BK 64
#define LDT 72           // A-tile padded row (bf16): 144 B -> <=2-way banks (free)

static __device__ __forceinline__ void gll16(const void* g, void* l) {
    __builtin_amdgcn_global_load_lds(
        (const __attribute__((address_space(1))) u32*)g,
        (__attribute__((address_space(3))) u32*)l, 16, 0, 0);
}

static __device__ inline bf16x8 cvt8(float4 a, float4 b) {
    bf16x8 v;
    v[0] = (bf16_t)a.x; v[1] = (bf16_t)a.y; v[2] = (bf16_t)a.z; v[3] = (bf16_t)a.w;
    v[4] = (bf16_t)b.x; v[5] = (bf16_t)b.y; v[6] = (bf16_t)b.z; v[7] = (bf16_t)b.w;
    return v;
}

// ---------------------------------------------------------------------------
// Prep: blocks 0..127 transpose W1 -> W1T bf16; block 128 Wg_eff + bias_eff;
// blocks 129..308 coordinate field cf. (No A-convert pass.)
__global__ __launch_bounds__(256) void prep_kernel(
    const float* __restrict__ W1, const float* __restrict__ W2,
    const float* __restrict__ b2, const float* __restrict__ Wg,
    const float* __restrict__ bg, float* __restrict__ ws)
{
    const int t = threadIdx.x;
    if (blockIdx.x < 128) {
        __shared__ bf16_t tile[64][72];
        const int k0 = (blockIdx.x & 15) * 64;
        const int n0 = (blockIdx.x >> 4) * 64;
        bf16_t* W1T = (bf16_t*)(ws + OFF_W1T);
#pragma unroll
        for (int i = 0; i < 4; ++i) {
            int idx = t + i * 256;
            int r = idx >> 4, ch = idx & 15;
            float4 v = *(const float4*)(W1 + (size_t)(k0 + r) * N1 + n0 + ch * 4);
            bf16_t* dst = &tile[r][ch * 4];
            dst[0] = (bf16_t)v.x; dst[1] = (bf16_t)v.y;
            dst[2] = (bf16_t)v.z; dst[3] = (bf16_t)v.w;
        }
        __syncthreads();
#pragma unroll
        for (int i = 0; i < 2; ++i) {
            int idx = t + i * 256;
            int nr = idx >> 3, kc = idx & 7;
            bf16x8 o;
#pragma unroll
            for (int j = 0; j < 8; ++j) o[j] = tile[kc * 8 + j][nr];
            *(bf16x8*)(W1T + (size_t)(n0 + nr) * K1 + k0 + kc * 8) = o;
        }
    } else if (blockIdx.x == 128) {
#pragma unroll
        for (int rep = 0; rep < 2; ++rep) {
            int j = t + rep * 256;
            float a0 = 0.f, a1 = 0.f, a2 = 0.f;
            for (int k = 0; k < 128; ++k) {
                float w = W2[j * 128 + k];
                a0 = fmaf(w, Wg[k * 3 + 0], a0);
                a1 = fmaf(w, Wg[k * 3 + 1], a1);
                a2 = fmaf(w, Wg[k * 3 + 2], a2);
            }
            ws[OFF_WGEFF + j * 3 + 0] = a0;
            ws[OFF_WGEFF + j * 3 + 1] = a1;
            ws[OFF_WGEFF + j * 3 + 2] = a2;
        }
        if (t < 3) {
            float s = 0.f;
            for (int k = 0; k < 128; ++k) s = fmaf(b2[k], Wg[k * 3 + t], s);
            ws[OFF_BIASEFF + t] = s;
        }
    } else {
        int e = (blockIdx.x - 129) * 256 + t;    // < 46080 exactly
        int c = e % 3;
        int p = e / 3;
        int x = p / NPY, y = p % NPY;
        float wpx = Wg[128 * 3 + c], wpy = Wg[129 * 3 + c];
        float wqx = Wg[130 * 3 + c], wqy = Wg[131 * 3 + c];
        auto aff = [&](int xx, int yy) -> float {
            return (float)(xx >> 4) * wpx + (float)(yy >> 4) * wpy
                 + (float)(xx & 15) * (1.f / 15.f) * wqx
                 + (float)(yy & 15) * (1.f / 15.f) * wqy;
        };
        auto deg = [&](int xx, int yy) -> float {
            return 1.f + (xx > 0) + (xx < NPX - 1) + (yy > 0) + (yy < NPY - 1);
        };
        float degc = deg(x, y);
        float s = 0.f;
        if (x > 0)       s += rsqrtf(deg(x - 1, y)) * aff(x - 1, y);
        if (x < NPX - 1) s += rsqrtf(deg(x + 1, y)) * aff(x + 1, y);
        if (y > 0)       s += rsqrtf(deg(x, y - 1)) * aff(x, y - 1);
        if (y < NPY - 1) s += rsqrtf(deg(x, y + 1)) * aff(x, y + 1);
        ws[OFF_CF + e] = rsqrtf(degc) * s + aff(x, y) / degc + bg[c];
    }
}

// ---------------------------------------------------------------------------
// GEMM: A reg-staged (r5-proven: f32 loads -> cvt8 -> ds_write into padded
// bf16 [2][64][72]); B via global_load_lds with rule-#21 involution swizzle
// (r11-proven: linear [2][64][64], source chunk ^ (row&7), same XOR on read).
// 960 blocks x 256 thr, 4 waves of 32x32, bijective XCD chunk swizzle.
// LDS 34.8 KB -> 4 blocks/CU.
__global__ __launch_bounds__(256) void gemm_kernel(
    const float* __restrict__ A,      // [7680,1024] f32
    const float* __restrict__ b1,     // [512]
    const float* __restrict__ ws,     // Wg_eff + W1T
    float* __restrict__ hw_part)      // [8][7680][3]
{
    __shared__ __align__(16) char smem[34816];
    bf16_t* sA = (bf16_t*)smem;                  // [2][64][72] = 18432 B
    bf16_t* sB = (bf16_t*)(smem + 18432);        // [2][64][64] = 16384 B
    float*  red = (float*)smem;                  // [64][32][3] (epilogue reuse)
    const bf16_t* W1T = (const bf16_t*)(ws + OFF_W1T);

    // XCD chunk swizzle (bijective: 960 = 8 * 120)
    const int bid = blockIdx.x;
    const int xcd = bid & 7;
    const int local = bid >> 3;                 // 0..119
    const int nblk = local & 7;                 // 0..7
    const int mblk = xcd * 15 + (local >> 3);   // 0..119
    const int m0 = mblk * BM;
    const int n0 = nblk * BN;

    const int t = threadIdx.x;
    const int lane = t & 63;
    const int wv = t >> 6;            // 0..3
    const int wr = wv >> 1, wc = wv & 1;
    const int l15 = lane & 15, hi = lane >> 4;
    const int x7 = l15 & 7;

    // ---- A staging (r5): thread t -> row t>>2 (0..63), quarter (t&3)*16
    const int srow = t >> 2;
    const int sq = (t & 3) << 4;
    const float* aptr = A + (size_t)(m0 + srow) * K1 + sq;
    const int swoff = srow * LDT + sq;

    // ---- B staging (r11): 2 gll/wave-instr per step, 8 rows x 128 B each
    const int rB0 = 8 * (2 * wv) + (lane >> 3);
    const int cB = (lane & 7) ^ (lane >> 3);
    const bf16_t* bSrc0 = W1T + (size_t)(n0 + rB0) * K1 + cB * 8;
    const bf16_t* bSrc1 = bSrc0 + (size_t)8 * K1;
    const int ldsB0 = (2 * wv + 0) * 512;       // bf16 elems (wave-uniform)
    const int ldsB1 = (2 * wv + 1) * 512;

    // fragment read offsets
    int aoff[2][2];   // [mi][kk]: (wr*32+mi*16+l15)*LDT + kk*32 + hi*8
    int boff[2][2];   // [ni][kk]: (wc*32+ni*16+l15)*64 + ((kk*4+hi)^x7)*8
#pragma unroll
    for (int mi = 0; mi < 2; ++mi)
#pragma unroll
        for (int kk = 0; kk < 2; ++kk) {
            aoff[mi][kk] = (wr * 32 + mi * 16 + l15) * LDT + kk * 32 + hi * 8;
            boff[mi][kk] = (wc * 32 + mi * 16 + l15) * 64 + ((kk * 4 + hi) ^ x7) * 8;
        }

    f32x4 acc[2][2];
#pragma unroll
    for (int i = 0; i < 2; ++i)
#pragma unroll
        for (int j = 0; j < 2; ++j) acc[i][j] = (f32x4)0.f;

    // prologue: stage ks=0 into buffer 0
    {
        float4 fa0 = *(const float4*)(aptr + 0);
        float4 fa1 = *(const float4*)(aptr + 4);
        float4 fa2 = *(const float4*)(aptr + 8);
        float4 fa3 = *(const float4*)(aptr + 12);
        *(bf16x8*)(sA + swoff)     = cvt8(fa0, fa1);
        *(bf16x8*)(sA + swoff + 8) = cvt8(fa2, fa3);
        gll16(bSrc0, sB + ldsB0);
        gll16(bSrc1, sB + ldsB1);
    }
    __syncthreads();

    int cur = 0;
    for (int ks = 0; ks < K1 / BK; ++ks) {
        float4 fa0, fa1, fa2, fa3;
        const bool pf = (ks < K1 / BK - 1);
        if (pf) {
            const float* ap = aptr + (ks + 1) * BK;
            fa0 = *(const float4*)(ap + 0);
            fa1 = *(const float4*)(ap + 4);
            fa2 = *(const float4*)(ap + 8);
            fa3 = *(const float4*)(ap + 12);
            const int kb = (ks + 1) * BK;
            const int nbB = (cur ^ 1) * 4096;
            gll16(bSrc0 + kb, sB + nbB + ldsB0);
            gll16(bSrc1 + kb, sB + nbB + ldsB1);
        }
        const bf16_t* cA = sA + cur * (BM * LDT);
        const bf16_t* cB2 = sB + cur * 4096;
        bf16x8 af[2][2], bfr[2][2];
#pragma unroll
        for (int i = 0; i < 2; ++i)
#pragma unroll
            for (int kk = 0; kk < 2; ++kk) {
                af[i][kk]  = *(const bf16x8*)(cA + aoff[i][kk]);
                bfr[i][kk] = *(const bf16x8*)(cB2 + boff[i][kk]);
            }
#pragma unroll
        for (int kk = 0; kk < 2; ++kk)
#pragma unroll
            for (int mi = 0; mi < 2; ++mi)
#pragma unroll
                for (int ni = 0; ni < 2; ++ni)
                    acc[mi][ni] = __builtin_amdgcn_mfma_f32_16x16x32_bf16(
                        af[mi][kk], bfr[ni][kk], acc[mi][ni], 0, 0, 0);
        if (pf) {
            bf16_t* nA = sA + (cur ^ 1) * (BM * LDT);
            *(bf16x8*)(nA + swoff)     = cvt8(fa0, fa1);
            *(bf16x8*)(nA + swoff + 8) = cvt8(fa2, fa3);
        }
        __syncthreads();
        cur ^= 1;
    }

    // epilogue: softplus + Wg_eff fold; per-lane partials -> LDS -> hw_part
    float b1v[2], wgv[2][3];
#pragma unroll
    for (int ni = 0; ni < 2; ++ni) {
        int n = n0 + wc * 32 + ni * 16 + l15;
        b1v[ni]    = b1[n];
        wgv[ni][0] = ws[OFF_WGEFF + n * 3 + 0];
        wgv[ni][1] = ws[OFF_WGEFF + n * 3 + 1];
        wgv[ni][2] = ws[OFF_WGEFF + n * 3 + 2];
    }
#pragma unroll
    for (int mi = 0; mi < 2; ++mi)
#pragma unroll
        for (int r = 0; r < 4; ++r) {
            float p0 = 0.f, p1 = 0.f, p2 = 0.f;
#pragma unroll
            for (int ni = 0; ni < 2; ++ni) {
                float z = acc[mi][ni][r] + b1v[ni];
                float sp = fmaxf(z, 0.f) + __logf(1.f + __expf(-fabsf(z)));
                p0 = fmaf(sp, wgv[ni][0], p0);
                p1 = fmaf(sp, wgv[ni][1], p1);
                p2 = fmaf(sp, wgv[ni][2], p2);
            }
            int ml = wr * 32 + mi * 16 + hi * 4 + r;   // 0..63 (bijective)
            int j  = wc * 16 + l15;                    // 0..31
            float* dst = red + (ml * 32 + j) * 3;
            dst[0] = p0; dst[1] = p1; dst[2] = p2;
        }
    __syncthreads();
    if (t < 192) {
        int m = t / 3, c = t - m * 3;
        float s = 0.f;
#pragma unroll
        for (int j = 0; j < 32; ++j) s += red[(m * 32 + j) * 3 + c];
        hw_part[((size_t)nblk * M_ROWS + m0 + m) * 3 + c] = s;
    }
}

// ---------------------------------------------------------------------------
// Fused hw-reduce + GCN stencil (r8/r10/r11-validated).
__global__ __launch_bounds__(384) void stencil_kernel(
    const float* __restrict__ ws, float* __restrict__ out)
{
    __shared__ float hwl[3][6][3];
    const int blk = blockIdx.x;
    const int b = blk / 10;
    const int px0 = blk % 10;
    const int x0 = px0 * 16;
    const int t = threadIdx.x;

    if (t < 54) {
        int j = t / 3, c = t - (t / 3) * 3;
        int dxi = j / 6, py = j % 6;
        int px = px0 - 1 + dxi;
        float v = 0.f;
        if (px >= 0 && px < 10) {
            int m = b * NPATCH + px * 6 + py;
            v = ws[OFF_BIASEFF + c];
#pragma unroll
            for (int s = 0; s < 8; ++s)
                v += ws[OFF_HWPART + ((size_t)s * M_ROWS + m) * 3 + c];
        }
        hwl[dxi][py][c] = v;
    }
    __syncthreads();

    const int xr = t / 24;
    const int y0 = (t - xr * 24) * 4;
    const int x = x0 + xr;
    const float* cf = ws + OFF_CF;

    auto deg = [&](int xx, int yy) -> float {
        return 1.f + (xx > 0) + (xx < NPX - 1) + (yy > 0) + (yy < NPY - 1);
    };
    auto hwp = [&](int xx, int yy) -> const float* {
        return &hwl[(xx >> 4) - (px0 - 1)][yy >> 4][0];
    };

    float res[4][3];
#pragma unroll
    for (int i = 0; i < 4; ++i) {
        int y = y0 + i;
        float degc = deg(x, y);
        float dinvc = rsqrtf(degc);
        float s0 = 0.f, s1 = 0.f, s2 = 0.f;
        auto tap = [&](int xx, int yy) {
            float dn = rsqrtf(deg(xx, yy));
            const float* h = hwp(xx, yy);
            s0 = fmaf(dn, h[0], s0);
            s1 = fmaf(dn, h[1], s1);
            s2 = fmaf(dn, h[2], s2);
        };
        if (x > 0)       tap(x - 1, y);
        if (x < NPX - 1) tap(x + 1, y);
        if (y > 0)       tap(x, y - 1);
        if (y < NPY - 1) tap(x, y + 1);
        const float* hs = hwp(x, y);
        const float* c = cf + (x * NPY + y) * 3;
        float inv_deg = 1.f / degc;
        res[i][0] = c[0] + fmaf(dinvc, s0, hs[0] * inv_deg);
        res[i][1] = c[1] + fmaf(dinvc, s1, hs[1] * inv_deg);
        res[i][2] = c[2] + fmaf(dinvc, s2, hs[2] * inv_deg);
    }
    float4 v0 = {res[0][0], res[0][1], res[0][2], res[1][0]};
    float4 v1 = {res[1][1], res[1][2], res[2][0], res[2][1]};
    float4 v2 = {res[2][2], res[3][0], res[3][1], res[3][2]};
    size_t p0 = ((size_t)b * NPX + x) * NPY + y0;
    float* o = out + p0 * 3;
    *(float4*)(o + 0) = v0;
    *(float4*)(o + 4) = v1;
    *(float4*)(o + 8) = v2;
}

// ---------------------------------------------------------------------------
extern "C" void kernel_launch(void* const* d_in, const int* in_sizes, int n_in,
                              void* d_out, int out_size, void* d_ws, size_t ws_size,
                              hipStream_t stream) {
    const float* pv = (const float*)d_in[0];
    const float* W1 = (const float*)d_in[1];
    const float* b1 = (const float*)d_in[2];
    const float* W2 = (const float*)d_in[3];
    const float* b2 = (const float*)d_in[4];
    const float* Wg = (const float*)d_in[5];
    const float* bg = (const float*)d_in[6];
    // d_in[7] = edge_index: fixed 4-neighbor grid, derived analytically

    float* ws = (float*)d_ws;
    float* out = (float*)d_out;

    hipLaunchKernelGGL(prep_kernel, dim3(309), dim3(256), 0, stream,
                       W1, W2, b2, Wg, bg, ws);
    hipLaunchKernelGGL(gemm_kernel, dim3(960), dim3(256), 0, stream,
                       pv, b1, ws, ws + OFF_HWPART);
    hipLaunchKernelGGL(stencil_kernel, dim3(1280), dim3(384), 0, stream,
                       ws, out);
}

// Round 14
// 51.879 us; speedup vs baseline: 1.1711x; 1.1421x over previous
//
#include <hip/hip_runtime.h>
#include <math.h>

typedef __bf16 bf16_t;
typedef __bf16 bf16x8 __attribute__((ext_vector_type(8)));
typedef float f32x4 __attribute__((ext_vector_type(4)));
typedef unsigned int u32;

// Problem constants
#define M_ROWS 7680      // bs(4) * seq(32) * 60 patches
#define N1 512
#define K1 1024
#define NPX 160
#define NPY 96
#define BDIM 128         // bs*seq
#define NPATCH 60
#define NPIX (BDIM*NPX*NPY)

// ws float offsets
#define OFF_WGEFF   0                        // 512*3
#define OFF_BIASEFF 1536                     // 3 (pad to 2048)
#define OFF_CF      2048                     // 15360*3 = 46080
#define OFF_HWPART  71168                    // 8*7680*3 = 184320
#define OFF_W1T     255488                   // bf16[512*1024] = 262144 float slots
#define OFF_ABF     517632                   // bf16[7680*1024] = 3932160 float slots
#define WS_NEED_BYTES ((size_t)OFF_ABF * 4 + (size_t)M_ROWS * K1 * 2)

// GEMM tiling
#define BM 64
#define BN 64
#define BK 64
#define LDT 72           // fallback path padded row

static __device__ __forceinline__ void gll16(const void* g, void* l) {
    __builtin_amdgcn_global_load_lds(
        (const __attribute__((address_space(1))) u32*)g,
        (__attribute__((address_space(3))) u32*)l, 16, 0, 0);
}

static __device__ inline bf16x8 cvt8(float4 a, float4 b) {
    bf16x8 v;
    v[0] = (bf16_t)a.x; v[1] = (bf16_t)a.y; v[2] = (bf16_t)a.z; v[3] = (bf16_t)a.w;
    v[4] = (bf16_t)b.x; v[5] = (bf16_t)b.y; v[6] = (bf16_t)b.z; v[7] = (bf16_t)b.w;
    return v;
}

// ---------------------------------------------------------------------------
// Merged prep: blocks 0..127 transpose W1 -> W1T bf16; block 128 Wg_eff +
// bias_eff; blocks 129..308 coordinate field cf; blocks 309..1268 (big-ws
// path) convert A f32 -> Abf bf16 (8 rows/block). The A-convert here is
// CHEAPER than any in-K-loop f32 handling (r12: +ds_read x2 & cvt, 43us;
// r13: +ds_write, 40us; r11 with this prep: GEMM ~20us).
__global__ __launch_bounds__(256) void prep_kernel(
    const float* __restrict__ A, const float* __restrict__ W1,
    const float* __restrict__ W2, const float* __restrict__ b2,
    const float* __restrict__ Wg, const float* __restrict__ bg,
    float* __restrict__ ws)
{
    const int t = threadIdx.x;
    if (blockIdx.x < 128) {
        __shared__ bf16_t tile[64][72];
        const int k0 = (blockIdx.x & 15) * 64;
        const int n0 = (blockIdx.x >> 4) * 64;
        bf16_t* W1T = (bf16_t*)(ws + OFF_W1T);
#pragma unroll
        for (int i = 0; i < 4; ++i) {
            int idx = t + i * 256;
            int r = idx >> 4, ch = idx & 15;
            float4 v = *(const float4*)(W1 + (size_t)(k0 + r) * N1 + n0 + ch * 4);
            bf16_t* dst = &tile[r][ch * 4];
            dst[0] = (bf16_t)v.x; dst[1] = (bf16_t)v.y;
            dst[2] = (bf16_t)v.z; dst[3] = (bf16_t)v.w;
        }
        __syncthreads();
#pragma unroll
        for (int i = 0; i < 2; ++i) {
            int idx = t + i * 256;
            int nr = idx >> 3, kc = idx & 7;
            bf16x8 o;
#pragma unroll
            for (int j = 0; j < 8; ++j) o[j] = tile[kc * 8 + j][nr];
            *(bf16x8*)(W1T + (size_t)(n0 + nr) * K1 + k0 + kc * 8) = o;
        }
    } else if (blockIdx.x == 128) {
#pragma unroll
        for (int rep = 0; rep < 2; ++rep) {
            int j = t + rep * 256;
            float a0 = 0.f, a1 = 0.f, a2 = 0.f;
            for (int k = 0; k < 128; ++k) {
                float w = W2[j * 128 + k];
                a0 = fmaf(w, Wg[k * 3 + 0], a0);
                a1 = fmaf(w, Wg[k * 3 + 1], a1);
                a2 = fmaf(w, Wg[k * 3 + 2], a2);
            }
            ws[OFF_WGEFF + j * 3 + 0] = a0;
            ws[OFF_WGEFF + j * 3 + 1] = a1;
            ws[OFF_WGEFF + j * 3 + 2] = a2;
        }
        if (t < 3) {
            float s = 0.f;
            for (int k = 0; k < 128; ++k) s = fmaf(b2[k], Wg[k * 3 + t], s);
            ws[OFF_BIASEFF + t] = s;
        }
    } else if (blockIdx.x < 309) {
        int e = (blockIdx.x - 129) * 256 + t;    // < 46080 exactly
        int c = e % 3;
        int p = e / 3;
        int x = p / NPY, y = p % NPY;
        float wpx = Wg[128 * 3 + c], wpy = Wg[129 * 3 + c];
        float wqx = Wg[130 * 3 + c], wqy = Wg[131 * 3 + c];
        auto aff = [&](int xx, int yy) -> float {
            return (float)(xx >> 4) * wpx + (float)(yy >> 4) * wpy
                 + (float)(xx & 15) * (1.f / 15.f) * wqx
                 + (float)(yy & 15) * (1.f / 15.f) * wqy;
        };
        auto deg = [&](int xx, int yy) -> float {
            return 1.f + (xx > 0) + (xx < NPX - 1) + (yy > 0) + (yy < NPY - 1);
        };
        float degc = deg(x, y);
        float s = 0.f;
        if (x > 0)       s += rsqrtf(deg(x - 1, y)) * aff(x - 1, y);
        if (x < NPX - 1) s += rsqrtf(deg(x + 1, y)) * aff(x + 1, y);
        if (y > 0)       s += rsqrtf(deg(x, y - 1)) * aff(x, y - 1);
        if (y < NPY - 1) s += rsqrtf(deg(x, y + 1)) * aff(x, y + 1);
        ws[OFF_CF + e] = rsqrtf(degc) * s + aff(x, y) / degc + bg[c];
    } else {
        // A f32 -> bf16 convert: block handles 8 rows = 1024 bf16x8 chunks
        bf16_t* Abf = (bf16_t*)(ws + OFF_ABF);
        const int m0 = (blockIdx.x - 309) * 8;
#pragma unroll
        for (int j = 0; j < 4; ++j) {
            int c = t + j * 256;                 // 0..1023
            int row = c >> 7;                    // 0..7
            int col8 = c & 127;                  // chunk of 8 elems
            const float* src = A + (size_t)(m0 + row) * K1 + col8 * 8;
            float4 v0 = *(const float4*)(src);
            float4 v1 = *(const float4*)(src + 4);
            *(bf16x8*)(Abf + (size_t)(m0 + row) * K1 + col8 * 8) = cvt8(v0, v1);
        }
    }
}

// ---------------------------------------------------------------------------
// GEMM (r11 measured-best): both operands bf16, staged via global_load_lds
// width=16 into LINEAR [64][64] LDS tiles; the 16-way read conflict of 128B
// rows is broken by the rule-#21 involution: inverse-swizzled SOURCE address
// (chunk ^ (row&7)) + the same XOR on the ds_read side. Zero ds_write, zero
// cvt in the K-loop. 960 blocks x 256 thr, 4 waves of 32x32, XCD chunk swizzle.
__global__ __launch_bounds__(256) void gemm_gll_kernel(
    const float* __restrict__ b1,     // [512]
    const float* __restrict__ ws,     // Wg_eff + W1T + Abf
    float* __restrict__ hw_part)      // [8][7680][3]
{
    __shared__ __align__(16) char smem[32768];
    bf16_t* sA = (bf16_t*)smem;                  // [2][64][64] bf16 = 16 KB
    bf16_t* sB = sA + 2 * 64 * 64;               // [2][64][64] bf16 = 16 KB
    float* red = (float*)smem;                   // [64][32][3] = 24 KB (reused)
    const bf16_t* W1T = (const bf16_t*)(ws + OFF_W1T);
    const bf16_t* Abf = (const bf16_t*)(ws + OFF_ABF);

    // XCD chunk swizzle (bijective: 960 = 8 * 120)
    const int bid = blockIdx.x;
    const int xcd = bid & 7;
    const int local = bid >> 3;                 // 0..119
    const int nblk = local & 7;                 // 0..7
    const int mblk = xcd * 15 + (local >> 3);   // 0..119
    const int m0 = mblk * BM;
    const int n0 = nblk * BN;

    const int t = threadIdx.x;
    const int lane = t & 63;
    const int wv = t >> 6;            // 0..3
    const int wr = wv >> 1, wc = wv & 1;
    const int l15 = lane & 15, hi = lane >> 4;
    const int x7 = l15 & 7;

    // staging (per wave, 2 gll instr per operand): instr i covers rows
    // 8*(2*wv+i) .. +8; lane l -> row +(l>>3), holds source chunk (l&7)^(l>>3)
    const int rbase0 = 8 * (2 * wv + 0) + (lane >> 3);
    const int c16src = (lane & 7) ^ (lane >> 3);
    const bf16_t* aSrc0 = Abf + (size_t)(m0 + rbase0) * K1 + c16src * 8;
    const bf16_t* aSrc1 = aSrc0 + (size_t)8 * K1;
    const bf16_t* bSrc0 = W1T + (size_t)(n0 + rbase0) * K1 + c16src * 8;
    const bf16_t* bSrc1 = bSrc0 + (size_t)8 * K1;
    // wave-uniform LDS bases (elems): instr i -> (2*wv+i)*512
    const int ldsOffA0 = (2 * wv + 0) * 512;
    const int ldsOffA1 = (2 * wv + 1) * 512;

    // fragment read offsets (elements within one [64][64] buffer), XOR-swizzled
    int aoff[2][2], boff[2][2];
#pragma unroll
    for (int mi = 0; mi < 2; ++mi)
#pragma unroll
        for (int kk = 0; kk < 2; ++kk) {
            aoff[mi][kk] = (wr * 32 + mi * 16 + l15) * 64 + ((kk * 4 + hi) ^ x7) * 8;
            boff[mi][kk] = (wc * 32 + mi * 16 + l15) * 64 + ((kk * 4 + hi) ^ x7) * 8;
        }

    f32x4 acc[2][2];
#pragma unroll
    for (int i = 0; i < 2; ++i)
#pragma unroll
        for (int j = 0; j < 2; ++j) acc[i][j] = (f32x4)0.f;

    // prologue: stage ks=0 into buffer 0
    gll16(aSrc0, sA + ldsOffA0);
    gll16(aSrc1, sA + ldsOffA1);
    gll16(bSrc0, sB + ldsOffA0);
    gll16(bSrc1, sB + ldsOffA1);
    __syncthreads();

    int cur = 0;
    for (int ks = 0; ks < K1 / BK; ++ks) {
        if (ks < K1 / BK - 1) {
            const int koff = (ks + 1) * BK;
            const int nb = (cur ^ 1) * 4096;
            gll16(aSrc0 + koff, sA + nb + ldsOffA0);
            gll16(aSrc1 + koff, sA + nb + ldsOffA1);
            gll16(bSrc0 + koff, sB + nb + ldsOffA0);
            gll16(bSrc1 + koff, sB + nb + ldsOffA1);
        }
        const bf16_t* cA = sA + cur * 4096;
        const bf16_t* cB = sB + cur * 4096;
        bf16x8 af[2][2], bfr[2][2];
#pragma unroll
        for (int i = 0; i < 2; ++i)
#pragma unroll
            for (int kk = 0; kk < 2; ++kk) {
                af[i][kk]  = *(const bf16x8*)(cA + aoff[i][kk]);
                bfr[i][kk] = *(const bf16x8*)(cB + boff[i][kk]);
            }
#pragma unroll
        for (int kk = 0; kk < 2; ++kk)
#pragma unroll
            for (int mi = 0; mi < 2; ++mi)
#pragma unroll
                for (int ni = 0; ni < 2; ++ni)
                    acc[mi][ni] = __builtin_amdgcn_mfma_f32_16x16x32_bf16(
                        af[mi][kk], bfr[ni][kk], acc[mi][ni], 0, 0, 0);
        __syncthreads();
        cur ^= 1;
    }

    // epilogue: softplus + Wg_eff fold; per-lane partials -> LDS -> hw_part
    float b1v[2], wgv[2][3];
#pragma unroll
    for (int ni = 0; ni < 2; ++ni) {
        int n = n0 + wc * 32 + ni * 16 + l15;
        b1v[ni]    = b1[n];
        wgv[ni][0] = ws[OFF_WGEFF + n * 3 + 0];
        wgv[ni][1] = ws[OFF_WGEFF + n * 3 + 1];
        wgv[ni][2] = ws[OFF_WGEFF + n * 3 + 2];
    }
#pragma unroll
    for (int mi = 0; mi < 2; ++mi)
#pragma unroll
        for (int r = 0; r < 4; ++r) {
            float p0 = 0.f, p1 = 0.f, p2 = 0.f;
#pragma unroll
            for (int ni = 0; ni < 2; ++ni) {
                float z = acc[mi][ni][r] + b1v[ni];
                float sp = fmaxf(z, 0.f) + __logf(1.f + __expf(-fabsf(z)));
                p0 = fmaf(sp, wgv[ni][0], p0);
                p1 = fmaf(sp, wgv[ni][1], p1);
                p2 = fmaf(sp, wgv[ni][2], p2);
            }
            int ml = wr * 32 + mi * 16 + hi * 4 + r;   // 0..63 (bijective)
            int j  = wc * 16 + l15;                    // 0..31
            float* dst = red + (ml * 32 + j) * 3;
            dst[0] = p0; dst[1] = p1; dst[2] = p2;
        }
    __syncthreads();
    if (t < 192) {
        int m = t / 3, c = t - m * 3;
        float s = 0.f;
#pragma unroll
        for (int j = 0; j < 32; ++j) s += red[(m * 32 + j) * 3 + c];
        hw_part[((size_t)nblk * M_ROWS + m0 + m) * 3 + c] = s;
    }
}

// ---------------------------------------------------------------------------
// FALLBACK GEMM (r10 verbatim, used only if ws too small): reg-staged.
__global__ __launch_bounds__(512, 8) void gemm_mfma_kernel(
    const float* __restrict__ A, const float* __restrict__ b1,
    const float* __restrict__ ws, float* __restrict__ hw_part)
{
    __shared__ __align__(16) char smem[36864];
    bf16_t* sA = (bf16_t*)smem;
    bf16_t* sB = sA + 2 * BM * LDT;
    float* red = (float*)smem;
    const bf16_t* W1T = (const bf16_t*)(ws + OFF_W1T);

    const int bid = blockIdx.x;
    const int xcd = bid & 7;
    const int local = bid >> 3;
    const int nblk = local & 7;
    const int mblk = xcd * 15 + (local >> 3);
    const int m0 = mblk * BM;
    const int n0 = nblk * BN;

    const int t = threadIdx.x;
    const int lane = t & 63;
    const int wv = t >> 6;
    const int wr = wv & 1;
    const int wcn = wv >> 1;
    const int l15 = lane & 15, hi = lane >> 4;

    const int srow = t >> 3;
    const int oct = (t & 7) << 3;
    const float*  aptr = A   + (size_t)(m0 + srow) * K1 + oct;
    const bf16_t* bptr = W1T + (size_t)(n0 + srow) * K1 + oct;
    const int swoff = srow * LDT + oct;

    f32x4 acc[2];
    acc[0] = (f32x4)0.f; acc[1] = (f32x4)0.f;

    {
        float4 fa0 = *(const float4*)(aptr + 0);
        float4 fa1 = *(const float4*)(aptr + 4);
        uint4  ub0 = *(const uint4*)(bptr);
        *(bf16x8*)(sA + swoff) = cvt8(fa0, fa1);
        *(uint4*)(sB + swoff)  = ub0;
    }
    __syncthreads();

    int cur = 0;
    for (int ks = 0; ks < K1 / BK; ++ks) {
        float4 fa0, fa1; uint4 ub0;
        const bool pf = (ks < K1 / BK - 1);
        if (pf) {
            const float*  ap = aptr + (ks + 1) * BK;
            const bf16_t* bp = bptr + (ks + 1) * BK;
            fa0 = *(const float4*)(ap + 0);
            fa1 = *(const float4*)(ap + 4);
            ub0 = *(const uint4*)(bp);
        }
        const bf16_t* cA = sA + cur * (BM * LDT);
        const bf16_t* cB = sB + cur * (BM * LDT);
        bf16x8 af[2][2], bfr[2];
#pragma unroll
        for (int kk = 0; kk < 2; ++kk) {
#pragma unroll
            for (int mi = 0; mi < 2; ++mi)
                af[mi][kk] = *(const bf16x8*)(cA + (wr * 32 + mi * 16 + l15) * LDT + kk * 32 + hi * 8);
            bfr[kk] = *(const bf16x8*)(cB + (wcn * 16 + l15) * LDT + kk * 32 + hi * 8);
        }
#pragma unroll
        for (int kk = 0; kk < 2; ++kk)
#pragma unroll
            for (int mi = 0; mi < 2; ++mi)
                acc[mi] = __builtin_amdgcn_mfma_f32_16x16x32_bf16(
                    af[mi][kk], bfr[kk], acc[mi], 0, 0, 0);
        if (pf) {
            bf16_t* nA = sA + (cur ^ 1) * (BM * LDT);
            bf16_t* nB = sB + (cur ^ 1) * (BM * LDT);
            *(bf16x8*)(nA + swoff) = cvt8(fa0, fa1);
            *(uint4*)(nB + swoff)  = ub0;
        }
        __syncthreads();
        cur ^= 1;
    }

    const int n = n0 + wcn * 16 + l15;
    const float bb = b1[n];
    const float wg0 = ws[OFF_WGEFF + n * 3 + 0];
    const float wg1 = ws[OFF_WGEFF + n * 3 + 1];
    const float wg2 = ws[OFF_WGEFF + n * 3 + 2];
    const int jslot = (wcn & 1) * 16 + l15;

    float p[2][4][3];
#pragma unroll
    for (int mi = 0; mi < 2; ++mi)
#pragma unroll
        for (int r = 0; r < 4; ++r) {
            float z = acc[mi][r] + bb;
            float sp = fmaxf(z, 0.f) + __logf(1.f + __expf(-fabsf(z)));
            p[mi][r][0] = sp * wg0;
            p[mi][r][1] = sp * wg1;
            p[mi][r][2] = sp * wg2;
        }
    __syncthreads();
    if (wcn < 2) {
#pragma unroll
        for (int mi = 0; mi < 2; ++mi)
#pragma unroll
            for (int r = 0; r < 4; ++r) {
                int ml = wr * 32 + mi * 16 + hi * 4 + r;
                float* dst = red + (ml * 32 + jslot) * 3;
                dst[0] = p[mi][r][0]; dst[1] = p[mi][r][1]; dst[2] = p[mi][r][2];
            }
    }
    __syncthreads();
    if (wcn >= 2) {
#pragma unroll
        for (int mi = 0; mi < 2; ++mi)
#pragma unroll
            for (int r = 0; r < 4; ++r) {
                int ml = wr * 32 + mi * 16 + hi * 4 + r;
                float* dst = red + (ml * 32 + jslot) * 3;
                dst[0] += p[mi][r][0]; dst[1] += p[mi][r][1]; dst[2] += p[mi][r][2];
            }
    }
    __syncthreads();
    if (t < 192) {
        int m = t / 3, c = t - m * 3;
        float s = 0.f;
#pragma unroll
        for (int j = 0; j < 32; ++j) s += red[(m * 32 + j) * 3 + c];
        hw_part[((size_t)nblk * M_ROWS + m0 + m) * 3 + c] = s;
    }
}

// ---------------------------------------------------------------------------
// Fused hw-reduce + GCN stencil (r8/r10/r11-validated).
__global__ __launch_bounds__(384) void stencil_kernel(
    const float* __restrict__ ws, float* __restrict__ out)
{
    __shared__ float hwl[3][6][3];
    const int blk = blockIdx.x;
    const int b = blk / 10;
    const int px0 = blk % 10;
    const int x0 = px0 * 16;
    const int t = threadIdx.x;

    if (t < 54) {
        int j = t / 3, c = t - (t / 3) * 3;
        int dxi = j / 6, py = j % 6;
        int px = px0 - 1 + dxi;
        float v = 0.f;
        if (px >= 0 && px < 10) {
            int m = b * NPATCH + px * 6 + py;
            v = ws[OFF_BIASEFF + c];
#pragma unroll
            for (int s = 0; s < 8; ++s)
                v += ws[OFF_HWPART + ((size_t)s * M_ROWS + m) * 3 + c];
        }
        hwl[dxi][py][c] = v;
    }
    __syncthreads();

    const int xr = t / 24;
    const int y0 = (t - xr * 24) * 4;
    const int x = x0 + xr;
    const float* cf = ws + OFF_CF;

    auto deg = [&](int xx, int yy) -> float {
        return 1.f + (xx > 0) + (xx < NPX - 1) + (yy > 0) + (yy < NPY - 1);
    };
    auto hwp = [&](int xx, int yy) -> const float* {
        return &hwl[(xx >> 4) - (px0 - 1)][yy >> 4][0];
    };

    float res[4][3];
#pragma unroll
    for (int i = 0; i < 4; ++i) {
        int y = y0 + i;
        float degc = deg(x, y);
        float dinvc = rsqrtf(degc);
        float s0 = 0.f, s1 = 0.f, s2 = 0.f;
        auto tap = [&](int xx, int yy) {
            float dn = rsqrtf(deg(xx, yy));
            const float* h = hwp(xx, yy);
            s0 = fmaf(dn, h[0], s0);
            s1 = fmaf(dn, h[1], s1);
            s2 = fmaf(dn, h[2], s2);
        };
        if (x > 0)       tap(x - 1, y);
        if (x < NPX - 1) tap(x + 1, y);
        if (y > 0)       tap(x, y - 1);
        if (y < NPY - 1) tap(x, y + 1);
        const float* hs = hwp(x, y);
        const float* c = cf + (x * NPY + y) * 3;
        float inv_deg = 1.f / degc;
        res[i][0] = c[0] + fmaf(dinvc, s0, hs[0] * inv_deg);
        res[i][1] = c[1] + fmaf(dinvc, s1, hs[1] * inv_deg);
        res[i][2] = c[2] + fmaf(dinvc, s2, hs[2] * inv_deg);
    }
    float4 v0 = {res[0][0], res[0][1], res[0][2], res[1][0]};
    float4 v1 = {res[1][1], res[1][2], res[2][0], res[2][1]};
    float4 v2 = {res[2][2], res[3][0], res[3][1], res[3][2]};
    size_t p0 = ((size_t)b * NPX + x) * NPY + y0;
    float* o = out + p0 * 3;
    *(float4*)(o + 0) = v0;
    *(float4*)(o + 4) = v1;
    *(float4*)(o + 8) = v2;
}

// ---------------------------------------------------------------------------
extern "C" void kernel_launch(void* const* d_in, const int* in_sizes, int n_in,
                              void* d_out, int out_size, void* d_ws, size_t ws_size,
                              hipStream_t stream) {
    const float* pv = (const float*)d_in[0];
    const float* W1 = (const float*)d_in[1];
    const float* b1 = (const float*)d_in[2];
    const float* W2 = (const float*)d_in[3];
    const float* b2 = (const float*)d_in[4];
    const float* Wg = (const float*)d_in[5];
    const float* bg = (const float*)d_in[6];
    // d_in[7] = edge_index: fixed 4-neighbor grid, derived analytically

    float* ws = (float*)d_ws;
    float* out = (float*)d_out;
    const bool big = ws_size >= WS_NEED_BYTES;

    if (big) {
        hipLaunchKernelGGL(prep_kernel, dim3(309 + 960), dim3(256), 0, stream,
                           pv, W1, W2, b2, Wg, bg, ws);
        hipLaunchKernelGGL(gemm_gll_kernel, dim3(960), dim3(256), 0, stream,
                           b1, ws, ws + OFF_HWPART);
    } else {
        hipLaunchKernelGGL(prep_kernel, dim3(309), dim3(256), 0, stream,
                           pv, W1, W2, b2, Wg, bg, ws);
        hipLaunchKernelGGL(gemm_mfma_kernel, dim3(960), dim3(512), 0, stream,
                           pv, b1, ws, ws + OFF_HWPART);
    }
    hipLaunchKernelGGL(stencil_kernel, dim3(1280), dim3(384), 0, stream,
                       ws, out);
}